// Round 7
// baseline (236.212 us; speedup 1.0000x reference)
//
#include <hip/hip_runtime.h>
#include <hip/hip_fp16.h>
#include <cmath>

#define TPB 256
#define NSLOPE 0.2f
#define SEPS 1e-16f

#define BSH 7                 // nodes per bucket = 128
#define BNODES 128
#define NBMAX 1024            // supports N up to 131072 at BSH=7
#define NCHUNK 256            // blocks for bucket scatter (longer per-bucket runs)
#define SCTPB 1024            // bscatter threads
#define SCSTAGE 6720          // bscatter per-chunk LDS staging (chunk=6642 at N=100k)
#define STAGE 2816            // per-bucket LDS sorted-edge staging (cap=2688 at N=100k)
#define MAXDEG 96             // per-wave LDS edge staging cap (P[deg>96] ~ 0 for Poisson(17))

__device__ __forceinline__ float lrelu(float v) { return v > 0.f ? v : NSLOPE * v; }
__device__ __forceinline__ float elu1(float v)  { return v > 0.f ? v : expm1f(v); }
__device__ __forceinline__ float elu1f(float v) { return v > 0.f ? v : __expf(v) - 1.f; }

// ---- prep: SD[0..3]=S1[h], SD[4..7]=D1[h]; init padded-bucket cursors (1/64B line) ----
__global__ void k_prep(const float* __restrict__ W1, const float* __restrict__ as1,
                       const float* __restrict__ ad1, float* __restrict__ SD,
                       unsigned* __restrict__ bucketCursor, int NB, unsigned cap) {
    int t = threadIdx.x;
    for (int i = t; i < NB; i += blockDim.x) bucketCursor[(size_t)i * 16] = (unsigned)i * cap;
    if (t < 8) {
        int h = t & 3;
        const float* att = (t >= 4) ? ad1 : as1;
        float acc = 0.f;
        #pragma unroll
        for (int c = 0; c < 8; ++c) acc += W1[h*8+c] * att[h*8+c];
        SD[t] = acc;
    }
}

// ---- bucket scatter (R3 form): hist -> hierarchical shfl scan -> claim ->
//      LDS bucket-sort of the chunk -> bucket-coalesced global writes ----
__global__ void k_bscatter(const int* __restrict__ srcI, const int* __restrict__ dstI,
                           int E, int N, int NB, int chunk,
                           unsigned* __restrict__ bucketCursor, int* __restrict__ pk) {
    __shared__ int cnt[NBMAX];
    __shared__ unsigned base[NBMAX];      // claimed global bases
    __shared__ int offl[NBMAX];           // local exclusive prefix
    __shared__ int rval[SCSTAGE];
    __shared__ unsigned short rbkt[SCSTAGE];
    __shared__ int wtot[16], woff[16];    // wave-scan scratch
    int t = threadIdx.x;
    int lane = t & 63, wv = t >> 6;
    int ET = E + N;
    int beg = blockIdx.x * chunk;
    int end = min(beg + chunk, ET);
    int m = end - beg;
    for (int i = t; i < NBMAX; i += blockDim.x) cnt[i] = 0;
    __syncthreads();
    for (int e = beg + t; e < end; e += blockDim.x) {
        int d = (e < E) ? dstI[e] : (e - E);
        atomicAdd(&cnt[d >> BSH], 1);
    }
    __syncthreads();
    // hierarchical inclusive scan over NBMAX=1024 bins (SCTPB==NBMAX)
    int v = cnt[t];
    int inc = v;
    #pragma unroll
    for (int off = 1; off < 64; off <<= 1) {
        int u = __shfl_up(inc, off);
        if (lane >= off) inc += u;
    }
    if (lane == 63) wtot[wv] = inc;
    __syncthreads();
    if (t < 16) {
        int xv = wtot[t];
        int sc_ = xv;
        #pragma unroll
        for (int off = 1; off < 16; off <<= 1) {
            int u = __shfl_up(sc_, off);
            if (t >= off) sc_ += u;
        }
        woff[t] = sc_ - xv;   // exclusive wave offset
    }
    __syncthreads();
    offl[t] = inc + woff[wv] - v;   // exclusive prefix within chunk
    if (t < NB) {
        base[t] = v ? atomicAdd(&bucketCursor[(size_t)t * 16], (unsigned)v) : 0u;
        cnt[t] = 0;
    }
    __syncthreads();
    if (m <= SCSTAGE) {
        for (int e = beg + t; e < end; e += blockDim.x) {
            int s, d;
            if (e < E) { s = srcI[e]; d = dstI[e]; } else { s = d = e - E; }
            int b = d >> BSH;
            int r = atomicAdd(&cnt[b], 1);
            int slot = offl[b] + r;
            rval[slot] = (s << BSH) | (d & (BNODES - 1));
            rbkt[slot] = (unsigned short)b;
        }
        __syncthreads();
        for (int slot = t; slot < m; slot += blockDim.x) {
            int b = rbkt[slot];
            pk[base[b] + (unsigned)(slot - offl[b])] = rval[slot];
        }
    } else {
        for (int e = beg + t; e < end; e += blockDim.x) {
            int s, d;
            if (e < E) { s = srcI[e]; d = dstI[e]; } else { s = d = e - E; }
            int b = d >> BSH;
            int r = atomicAdd(&cnt[b], 1);
            pk[base[b] + (unsigned)r] = (s << BSH) | (d & (BNODES - 1));
        }
    }
}

// ---- merged sort + layer-1 + h2/att: pk read ONCE (praw UNION lds1, zero LDS
//      growth -> 5 blocks/CU kept); 2-barrier shfl scan for the 128-bin prefix. ----
__global__ void k_sl1h2(const int* __restrict__ pk, const unsigned* __restrict__ bucketCursor,
                        unsigned cap,
                        const float* __restrict__ x, const float* __restrict__ SD,
                        const float* __restrict__ W1, const float* __restrict__ b1,
                        const float* __restrict__ W2, const float* __restrict__ attS,
                        const float* __restrict__ attD, int N,
                        unsigned* __restrict__ offsets, int* __restrict__ sortedSrc,
                        __half* __restrict__ h2h, float* __restrict__ aS, float* __restrict__ aD) {
    __shared__ __align__(16) char upool[BNODES * 36 * 4];
    int* praw = (int*)upool;
    float (*lds1)[36] = (float (*)[36])upool;
    __shared__ int sorted[STAGE];
    __shared__ int cnt[BNODES];
    __shared__ int offl[BNODES];
    __shared__ int w0tot;
    int b = blockIdx.x, t = threadIdx.x;
    unsigned rbeg = (unsigned)b * cap;
    int m = (int)(bucketCursor[(size_t)b * 16] - rbeg);
    bool inLds = (m <= STAGE);
    int base = b << BSH;
    if (t < BNODES) cnt[t] = 0;
    __syncthreads();
    // pass 1: single global read of pk; stage into LDS + histogram
    if (inLds) {
        for (int i = t; i < m; i += TPB) {
            int p = pk[rbeg + i];
            praw[i] = p;
            atomicAdd(&cnt[p & (BNODES - 1)], 1);
        }
    } else {
        for (int i = t; i < m; i += TPB) atomicAdd(&cnt[pk[rbeg + i] & (BNODES - 1)], 1);
    }
    __syncthreads();
    // 128-bin exclusive prefix: per-wave shfl scan + single cross-wave fixup
    int v = (t < BNODES) ? cnt[t] : 0;
    int inc = v;
    #pragma unroll
    for (int off = 1; off < 64; off <<= 1) {
        int u = __shfl_up(inc, off);
        if ((t & 63) >= off) inc += u;
    }
    if (t == 63) w0tot = inc;
    __syncthreads();
    if (t >= 64 && t < BNODES) inc += w0tot;
    if (t < BNODES) {
        int ex = inc - v;
        int d = base + t;
        if (d < N) offsets[d] = ((rbeg + (unsigned)ex) << 10) | (unsigned)v;
        cnt[t] = 0;
        offl[t] = ex;
    }
    __syncthreads();
    // pass 2: reorder (LDS->LDS when staged), then coalesced global write
    if (inLds) {
        for (int i = t; i < m; i += TPB) {
            int p = praw[i];
            int dl = p & (BNODES - 1);
            int r = atomicAdd(&cnt[dl], 1);
            sorted[offl[dl] + r] = p >> BSH;
        }
        __syncthreads();
        for (int i = t; i < m; i += TPB) sortedSrc[rbeg + i] = sorted[i];
    } else {
        for (int i = t; i < m; i += TPB) {
            int p = pk[rbeg + i];
            int dl = p & (BNODES - 1);
            int r = atomicAdd(&cnt[dl], 1);
            sortedSrc[rbeg + (unsigned)(offl[dl] + r)] = p >> BSH;
        }
        __syncthreads();
    }
    __syncthreads();          // praw dead from here; lds1 live
    // layer-1 softmax: 2 threads/node; edge indices from LDS sorted[]
    int n = t >> 1, half = t & 1;
    int d2 = base + n;
    bool active = (d2 < N);
    float s0 = 0.f, s1 = 0.f, s2 = 0.f, s3 = 0.f;
    float g0 = 0.f, g1 = 0.f, g2 = 0.f, g3 = 0.f;
    if (active) {
        int deg = cnt[n];
        int lbeg = offl[n];
        float xd = x[d2];
        float S0 = SD[0], S1 = SD[1], S2 = SD[2], S3 = SD[3];
        float D0 = xd*SD[4], D1 = xd*SD[5], D2 = xd*SD[6], D3 = xd*SD[7];
        int dh = (deg + 1) >> 1;
        int i = lbeg + (half ? dh : 0);
        int rem = half ? (deg - dh) : dh;
        for (; rem >= 2; rem -= 2, i += 2) {
            int a0 = inLds ? sorted[i]   : sortedSrc[rbeg + i];
            int a1 = inLds ? sorted[i+1] : sortedSrc[rbeg + i + 1];
            float x0 = x[a0], x1 = x[a1];
            float p;
            p = __expf(lrelu(x0*S0 + D0)); s0 += p; g0 += p * x0;
            p = __expf(lrelu(x0*S1 + D1)); s1 += p; g1 += p * x0;
            p = __expf(lrelu(x0*S2 + D2)); s2 += p; g2 += p * x0;
            p = __expf(lrelu(x0*S3 + D3)); s3 += p; g3 += p * x0;
            p = __expf(lrelu(x1*S0 + D0)); s0 += p; g0 += p * x1;
            p = __expf(lrelu(x1*S1 + D1)); s1 += p; g1 += p * x1;
            p = __expf(lrelu(x1*S2 + D2)); s2 += p; g2 += p * x1;
            p = __expf(lrelu(x1*S3 + D3)); s3 += p; g3 += p * x1;
        }
        if (rem > 0) {
            int a0 = inLds ? sorted[i] : sortedSrc[rbeg + i];
            float xs = x[a0];
            float p;
            p = __expf(lrelu(xs*S0 + D0)); s0 += p; g0 += p * xs;
            p = __expf(lrelu(xs*S1 + D1)); s1 += p; g1 += p * xs;
            p = __expf(lrelu(xs*S2 + D2)); s2 += p; g2 += p * xs;
            p = __expf(lrelu(xs*S3 + D3)); s3 += p; g3 += p * xs;
        }
    }
    s0 += __shfl_xor(s0, 1); s1 += __shfl_xor(s1, 1);
    s2 += __shfl_xor(s2, 1); s3 += __shfl_xor(s3, 1);
    g0 += __shfl_xor(g0, 1); g1 += __shfl_xor(g1, 1);
    g2 += __shfl_xor(g2, 1); g3 += __shfl_xor(g3, 1);
    if (active) {
        float gg[4];
        gg[0] = g0 / (s0 + SEPS); gg[1] = g1 / (s1 + SEPS);
        gg[2] = g2 / (s2 + SEPS); gg[3] = g3 / (s3 + SEPS);
        int h0 = half * 2;                 // each half-thread writes 2 heads
        #pragma unroll
        for (int hh = 0; hh < 2; ++hh)
            #pragma unroll
            for (int cc = 0; cc < 8; ++cc)
                lds1[n][(h0+hh)*8+cc] = elu1(gg[h0+hh] * W1[(h0+hh)*8+cc] + b1[(h0+hh)*8+cc]);
    }
    __syncthreads();
    // h2 = lds1 @ W2 (+ att coeffs); W2 column in 32 VGPRs, row via b128 reads.
    int lane = t & 63;                    // channel j
    int sub = t >> 6;                     // wave id 0..3
    float w2r[32];
    #pragma unroll
    for (int k = 0; k < 32; ++k) w2r[k] = W2[k*64 + lane];
    float attSl = attS[lane], attDl = attD[lane];
    int nCnt = min(BNODES, N - base);
    for (int nn = sub; nn < nCnt; nn += 4) {
        const float4* row4 = (const float4*)lds1[nn];
        float acc = 0.f;
        #pragma unroll
        for (int k4 = 0; k4 < 8; ++k4) {
            float4 rv = row4[k4];
            acc += rv.x*w2r[4*k4] + rv.y*w2r[4*k4+1] + rv.z*w2r[4*k4+2] + rv.w*w2r[4*k4+3];
        }
        int node = base + nn;
        h2h[(size_t)node*64 + lane] = __float2half(acc);
        float ps = acc * attSl;
        float pd = acc * attDl;
        #pragma unroll
        for (int mm = 1; mm < 8; mm <<= 1) {
            ps += __shfl_xor(ps, mm);
            pd += __shfl_xor(pd, mm);
        }
        int hh = lane >> 3, cc = lane & 7;
        if (cc == 0) aS[(size_t)node*8 + hh] = ps;
        if (cc == 1) aD[(size_t)node*8 + hh] = pd;
    }
}

// ---- layer 2 HALF-HEAD pass: heads HB..HB+3 (32 channels). Wave per node.
//   lH4 = lane&15 -> channel pair; q = lane>>4 -> edge slot (4 edges/group).
//   Per record, 16 lanes read 16 consecutive half2 = exactly one 64B line
//   (record halves are line-aligned, h2h 128B-aligned). Per-pass gather
//   working set ~9.6MB (vs 16MB) -> better XCD-L2 hit rate.
//   HB=0 writes partial tt to tmp; HB=4 adds tmp + fcb -> out. ----
template<int HB>
__global__ void k_aggh(const unsigned* __restrict__ offsets, const int* __restrict__ ss,
                       const float* __restrict__ aS, const float* __restrict__ aD,
                       const __half* __restrict__ h2h, const float* __restrict__ b2,
                       const float* __restrict__ fcw, const float* __restrict__ fcb,
                       const float* __restrict__ tmpIn, float* __restrict__ tmpOut,
                       float* __restrict__ out, int N) {
    __shared__ int sl[4][MAXDEG];
    int lane = threadIdx.x & 63;
    int w = threadIdx.x >> 6;
    int d = blockIdx.x * 4 + w;
    if (d >= N) return;
    unsigned u = offsets[d];
    unsigned beg = u >> 10;
    int deg = (int)(u & 1023u);
    int lH4 = lane & 15;            // channel pair within pass
    int q   = lane >> 4;            // edge slot 0..3
    int h4  = lH4 >> 2;             // head within pass; global head = HB + h4
    const __half2* __restrict__ hp = (const __half2*)h2h;   // 32 half2 per record
    float sum = 0.f, ax = 0.f, ay = 0.f;
    float adv = aD[(unsigned)d * 8u + (unsigned)(HB + h4)];
    if (deg <= MAXDEG) {
        int degPad = (deg + 3) & ~3;
        for (int j = lane; j < degPad; j += 64) sl[w][j] = ss[beg + (unsigned)min(j, deg - 1)];
        for (int e = 0; e < degPad; e += 4) {
            int bi = e + q;
            int s = sl[w][bi];
            float a = aS[(unsigned)s * 8u + (unsigned)(HB + h4)];
            float2 g = __half22float2(hp[(unsigned)s * 32u + (unsigned)(HB * 4 + lH4)]);
            float p = __expf(lrelu(a + adv));
            if (e + 4 > deg) {            // wave-uniform, last group only
                if (bi >= deg) p = 0.f;
            }
            ax += p * g.x; ay += p * g.y; sum += p;
        }
    } else {
        // fallback (statistically never): quarters take strided edges
        for (int e = q; e < deg; e += 4) {
            int s = ss[beg + e];
            float p = __expf(lrelu(aS[(unsigned)s * 8u + (unsigned)(HB + h4)] + adv));
            float2 g = __half22float2(hp[(unsigned)s * 32u + (unsigned)(HB * 4 + lH4)]);
            ax += p * g.x; ay += p * g.y; sum += p;
        }
    }
    // reduce across the 4 edge slots (lanes with same lH4)
    ax  += __shfl_xor(ax, 16);  ax  += __shfl_xor(ax, 32);
    ay  += __shfl_xor(ay, 16);  ay  += __shfl_xor(ay, 32);
    sum += __shfl_xor(sum, 16); sum += __shfl_xor(sum, 32);
    float inv = 1.f / (sum + SEPS);
    int c0 = HB * 8 + 2 * lH4;
    float tt = elu1f(ax * inv + b2[c0])     * fcw[c0]
             + elu1f(ay * inv + b2[c0 + 1]) * fcw[c0 + 1];
    #pragma unroll
    for (int m = 8; m; m >>= 1) tt += __shfl_xor(tt, m);
    if (lane == 0) {
        if (HB == 0) tmpOut[d] = tt;
        else         out[d] = tt + tmpIn[d] + fcb[0];
    }
}

extern "C" void kernel_launch(void* const* d_in, const int* in_sizes, int n_in,
                              void* d_out, int out_size, void* d_ws, size_t ws_size,
                              hipStream_t stream) {
    const float* x    = (const float*)d_in[0];
    const int*   ei   = (const int*)  d_in[1];
    const float* W1   = (const float*)d_in[2];
    const float* as1  = (const float*)d_in[3];
    const float* ad1  = (const float*)d_in[4];
    const float* b1   = (const float*)d_in[5];
    const float* W2   = (const float*)d_in[6];
    const float* attS2= (const float*)d_in[7];
    const float* attD2= (const float*)d_in[8];
    const float* b2   = (const float*)d_in[9];
    const float* fcw  = (const float*)d_in[10];
    const float* fcb  = (const float*)d_in[11];
    float* out = (float*)d_out;

    int N = in_sizes[0];          // x is [N,1]
    int E = in_sizes[1] / 2;      // edge_index is [2,E]
    int ET = E + N;               // with self-loops
    int NB = (N + BNODES - 1) / BNODES;   // 128-node coarse buckets (<= NBMAX)
    // padded bucket capacity: mean + 512 (~11 sigma for Binomial(ET,1/NB)), 4-aligned
    unsigned cap = (unsigned)((ET + NB - 1) / NB + 512);
    cap = (cap + 3u) & ~3u;
    size_t padded = (size_t)NB * cap;

    const int* srcI = ei;
    const int* dstI = ei + E;

    float* ws = (float*)d_ws;
    size_t off = 0;
    float*    SD           = ws + off; off += 16;
    unsigned* bucketCursor = (unsigned*)(ws + off); off += (size_t)NBMAX * 16;
    unsigned* offsets      = (unsigned*)(ws + off); off += (size_t)N + 16;
    int*      pk           = (int*)(ws + off); off += padded;
    int*      sortedSrc    = (int*)(ws + off); off += padded;
    float*    aS2          = ws + off; off += (size_t)N * 8;
    float*    aD2          = ws + off; off += (size_t)N * 8;
    off = (off + 31) & ~(size_t)31;       // 128B-align h2h (head halves line-aligned)
    __half*   h2h          = (__half*)(ws + off); off += (size_t)N * 32;  // N*64 halves
    float*    tmp          = ws + off; off += (size_t)N;

    k_prep<<<1, 1024, 0, stream>>>(W1, as1, ad1, SD, bucketCursor, NB, cap);

    int chunk = (ET + NCHUNK - 1) / NCHUNK;
    k_bscatter<<<NCHUNK, SCTPB, 0, stream>>>(srcI, dstI, E, N, NB, chunk, bucketCursor, pk);
    k_sl1h2   <<<NB, TPB, 0, stream>>>(pk, bucketCursor, cap, x, SD, W1, b1, W2, attS2, attD2,
                                       N, offsets, sortedSrc, h2h, aS2, aD2);
    k_aggh<0> <<<(N + 3) / 4, TPB, 0, stream>>>(offsets, sortedSrc, aS2, aD2, h2h,
                                                b2, fcw, fcb, nullptr, tmp, nullptr, N);
    k_aggh<4> <<<(N + 3) / 4, TPB, 0, stream>>>(offsets, sortedSrc, aS2, aD2, h2h,
                                                b2, fcw, fcb, tmp, nullptr, out, N);
}

// Round 10
// 212.241 us; speedup vs baseline: 1.1129x; 1.1129x over previous
//
#include <hip/hip_runtime.h>
#include <hip/hip_fp16.h>
#include <cmath>

#define TPB 256
#define NSLOPE 0.2f
#define SEPS 1e-16f

#define BSH 7                 // nodes per bucket = 128
#define BNODES 128
#define NBMAX 1024            // supports N up to 131072 at BSH=7
#define NCHUNK 256            // blocks for bucket scatter (longer per-bucket runs)
#define SCTPB 1024            // bscatter threads
#define SCSTAGE 6720          // bscatter per-chunk LDS staging (chunk=6642 at N=100k)
#define STAGE 2816            // per-bucket LDS sorted-edge staging (cap=2688 at N=100k)
#define MAXDEG 96             // per-wave LDS edge staging cap (P[deg>96] ~ 0 for Poisson(17))

__device__ __forceinline__ float lrelu(float v) { return v > 0.f ? v : NSLOPE * v; }
__device__ __forceinline__ float elu1(float v)  { return v > 0.f ? v : expm1f(v); }
__device__ __forceinline__ float elu1f(float v) { return v > 0.f ? v : __expf(v) - 1.f; }

// ---- bucket scatter (R6 form, cursor-as-offset): hist -> hierarchical shfl scan ->
//      claim -> LDS bucket-sort of the chunk -> bucket-coalesced global writes.
//      bucketCursor starts at 0 (memset) and counts per-bucket offsets; absolute
//      position = b*cap + offset, added at the write site. ----
__global__ void k_bscatter(const int* __restrict__ srcI, const int* __restrict__ dstI,
                           int E, int N, int NB, int chunk, unsigned cap,
                           unsigned* __restrict__ bucketCursor, int* __restrict__ pk) {
    __shared__ int cnt[NBMAX];
    __shared__ unsigned base[NBMAX];      // claimed per-bucket offsets
    __shared__ int offl[NBMAX];           // local exclusive prefix
    __shared__ int rval[SCSTAGE];
    __shared__ unsigned short rbkt[SCSTAGE];
    __shared__ int wtot[16], woff[16];    // wave-scan scratch
    int t = threadIdx.x;
    int lane = t & 63, wv = t >> 6;
    int ET = E + N;
    int beg = blockIdx.x * chunk;
    int end = min(beg + chunk, ET);
    int m = end - beg;
    for (int i = t; i < NBMAX; i += blockDim.x) cnt[i] = 0;
    __syncthreads();
    for (int e = beg + t; e < end; e += blockDim.x) {
        int d = (e < E) ? dstI[e] : (e - E);
        atomicAdd(&cnt[d >> BSH], 1);
    }
    __syncthreads();
    // hierarchical inclusive scan over NBMAX=1024 bins (SCTPB==NBMAX)
    int v = cnt[t];
    int inc = v;
    #pragma unroll
    for (int off = 1; off < 64; off <<= 1) {
        int u = __shfl_up(inc, off);
        if (lane >= off) inc += u;
    }
    if (lane == 63) wtot[wv] = inc;
    __syncthreads();
    if (t < 16) {
        int xv = wtot[t];
        int sc_ = xv;
        #pragma unroll
        for (int off = 1; off < 16; off <<= 1) {
            int u = __shfl_up(sc_, off);
            if (t >= off) sc_ += u;
        }
        woff[t] = sc_ - xv;   // exclusive wave offset
    }
    __syncthreads();
    offl[t] = inc + woff[wv] - v;   // exclusive prefix within chunk
    if (t < NB) {
        base[t] = v ? atomicAdd(&bucketCursor[(size_t)t * 16], (unsigned)v) : 0u;
        cnt[t] = 0;
    }
    __syncthreads();
    if (m <= SCSTAGE) {
        for (int e = beg + t; e < end; e += blockDim.x) {
            int s, d;
            if (e < E) { s = srcI[e]; d = dstI[e]; } else { s = d = e - E; }
            int b = d >> BSH;
            int r = atomicAdd(&cnt[b], 1);
            int slot = offl[b] + r;
            rval[slot] = (s << BSH) | (d & (BNODES - 1));
            rbkt[slot] = (unsigned short)b;
        }
        __syncthreads();
        for (int slot = t; slot < m; slot += blockDim.x) {
            int b = rbkt[slot];
            pk[(size_t)b * cap + base[b] + (unsigned)(slot - offl[b])] = rval[slot];
        }
    } else {
        for (int e = beg + t; e < end; e += blockDim.x) {
            int s, d;
            if (e < E) { s = srcI[e]; d = dstI[e]; } else { s = d = e - E; }
            int b = d >> BSH;
            int r = atomicAdd(&cnt[b], 1);
            pk[(size_t)b * cap + base[b] + (unsigned)r] = (s << BSH) | (d & (BNODES - 1));
        }
    }
}

// ---- merged sort + layer-1 + h2/att (R6 form): pk read ONCE (praw UNION lds1,
//      zero LDS growth -> 5 blocks/CU); 2-barrier shfl scan; SD (8 att-dot
//      scalars) computed per-block in LDS — k_prep kernel eliminated. ----
__global__ void k_sl1h2(const int* __restrict__ pk, const unsigned* __restrict__ bucketCursor,
                        unsigned cap,
                        const float* __restrict__ x,
                        const float* __restrict__ as1, const float* __restrict__ ad1,
                        const float* __restrict__ W1, const float* __restrict__ b1,
                        const float* __restrict__ W2, const float* __restrict__ attS,
                        const float* __restrict__ attD, int N,
                        unsigned* __restrict__ offsets, int* __restrict__ sortedSrc,
                        __half* __restrict__ h2h, float* __restrict__ aS, float* __restrict__ aD) {
    __shared__ __align__(16) char upool[BNODES * 36 * 4];
    int* praw = (int*)upool;
    float (*lds1)[36] = (float (*)[36])upool;
    __shared__ int sorted[STAGE];
    __shared__ int cnt[BNODES];
    __shared__ int offl[BNODES];
    __shared__ float SDs[8];
    __shared__ int w0tot;
    int b = blockIdx.x, t = threadIdx.x;
    unsigned rbeg = (unsigned)b * cap;
    int m = (int)bucketCursor[(size_t)b * 16];
    bool inLds = (m <= STAGE);
    int base = b << BSH;
    if (t < BNODES) cnt[t] = 0;
    if (t < 8) {                           // per-block SD: S1[h] / D1[h]
        int h = t & 3;
        const float* att = (t >= 4) ? ad1 : as1;
        float acc = 0.f;
        #pragma unroll
        for (int c = 0; c < 8; ++c) acc += W1[h*8+c] * att[h*8+c];
        SDs[t] = acc;
    }
    __syncthreads();
    // pass 1: single global read of pk; stage into LDS + histogram
    if (inLds) {
        for (int i = t; i < m; i += TPB) {
            int p = pk[rbeg + i];
            praw[i] = p;
            atomicAdd(&cnt[p & (BNODES - 1)], 1);
        }
    } else {
        for (int i = t; i < m; i += TPB) atomicAdd(&cnt[pk[rbeg + i] & (BNODES - 1)], 1);
    }
    __syncthreads();
    // 128-bin exclusive prefix: per-wave shfl scan + single cross-wave fixup
    int v = (t < BNODES) ? cnt[t] : 0;
    int inc = v;
    #pragma unroll
    for (int off = 1; off < 64; off <<= 1) {
        int u = __shfl_up(inc, off);
        if ((t & 63) >= off) inc += u;
    }
    if (t == 63) w0tot = inc;
    __syncthreads();
    if (t >= 64 && t < BNODES) inc += w0tot;
    if (t < BNODES) {
        int ex = inc - v;
        int d = base + t;
        if (d < N) offsets[d] = ((rbeg + (unsigned)ex) << 10) | (unsigned)v;
        cnt[t] = 0;
        offl[t] = ex;
    }
    __syncthreads();
    // pass 2: reorder (LDS->LDS when staged), then coalesced global write
    if (inLds) {
        for (int i = t; i < m; i += TPB) {
            int p = praw[i];
            int dl = p & (BNODES - 1);
            int r = atomicAdd(&cnt[dl], 1);
            sorted[offl[dl] + r] = p >> BSH;
        }
        __syncthreads();
        for (int i = t; i < m; i += TPB) sortedSrc[rbeg + i] = sorted[i];
    } else {
        for (int i = t; i < m; i += TPB) {
            int p = pk[rbeg + i];
            int dl = p & (BNODES - 1);
            int r = atomicAdd(&cnt[dl], 1);
            sortedSrc[rbeg + (unsigned)(offl[dl] + r)] = p >> BSH;
        }
        __syncthreads();
    }
    __syncthreads();          // praw dead from here; lds1 live
    // layer-1 softmax: 2 threads/node; edge indices from LDS sorted[]
    int n = t >> 1, half = t & 1;
    int d2 = base + n;
    bool active = (d2 < N);
    float s0 = 0.f, s1 = 0.f, s2 = 0.f, s3 = 0.f;
    float g0 = 0.f, g1 = 0.f, g2 = 0.f, g3 = 0.f;
    if (active) {
        int deg = cnt[n];
        int lbeg = offl[n];
        float xd = x[d2];
        float S0 = SDs[0], S1 = SDs[1], S2 = SDs[2], S3 = SDs[3];
        float D0 = xd*SDs[4], D1 = xd*SDs[5], D2 = xd*SDs[6], D3 = xd*SDs[7];
        int dh = (deg + 1) >> 1;
        int i = lbeg + (half ? dh : 0);
        int rem = half ? (deg - dh) : dh;
        for (; rem >= 2; rem -= 2, i += 2) {
            int a0 = inLds ? sorted[i]   : sortedSrc[rbeg + i];
            int a1 = inLds ? sorted[i+1] : sortedSrc[rbeg + i + 1];
            float x0 = x[a0], x1 = x[a1];
            float p;
            p = __expf(lrelu(x0*S0 + D0)); s0 += p; g0 += p * x0;
            p = __expf(lrelu(x0*S1 + D1)); s1 += p; g1 += p * x0;
            p = __expf(lrelu(x0*S2 + D2)); s2 += p; g2 += p * x0;
            p = __expf(lrelu(x0*S3 + D3)); s3 += p; g3 += p * x0;
            p = __expf(lrelu(x1*S0 + D0)); s0 += p; g0 += p * x1;
            p = __expf(lrelu(x1*S1 + D1)); s1 += p; g1 += p * x1;
            p = __expf(lrelu(x1*S2 + D2)); s2 += p; g2 += p * x1;
            p = __expf(lrelu(x1*S3 + D3)); s3 += p; g3 += p * x1;
        }
        if (rem > 0) {
            int a0 = inLds ? sorted[i] : sortedSrc[rbeg + i];
            float xs = x[a0];
            float p;
            p = __expf(lrelu(xs*S0 + D0)); s0 += p; g0 += p * xs;
            p = __expf(lrelu(xs*S1 + D1)); s1 += p; g1 += p * xs;
            p = __expf(lrelu(xs*S2 + D2)); s2 += p; g2 += p * xs;
            p = __expf(lrelu(xs*S3 + D3)); s3 += p; g3 += p * xs;
        }
    }
    s0 += __shfl_xor(s0, 1); s1 += __shfl_xor(s1, 1);
    s2 += __shfl_xor(s2, 1); s3 += __shfl_xor(s3, 1);
    g0 += __shfl_xor(g0, 1); g1 += __shfl_xor(g1, 1);
    g2 += __shfl_xor(g2, 1); g3 += __shfl_xor(g3, 1);
    if (active) {
        float gg[4];
        gg[0] = g0 / (s0 + SEPS); gg[1] = g1 / (s1 + SEPS);
        gg[2] = g2 / (s2 + SEPS); gg[3] = g3 / (s3 + SEPS);
        int h0 = half * 2;                 // each half-thread writes 2 heads
        #pragma unroll
        for (int hh = 0; hh < 2; ++hh)
            #pragma unroll
            for (int cc = 0; cc < 8; ++cc)
                lds1[n][(h0+hh)*8+cc] = elu1(gg[h0+hh] * W1[(h0+hh)*8+cc] + b1[(h0+hh)*8+cc]);
    }
    __syncthreads();
    // h2 = lds1 @ W2 (+ att coeffs); W2 column in 32 VGPRs, row via b128 reads.
    int lane = t & 63;                    // channel j
    int sub = t >> 6;                     // wave id 0..3
    float w2r[32];
    #pragma unroll
    for (int k = 0; k < 32; ++k) w2r[k] = W2[k*64 + lane];
    float attSl = attS[lane], attDl = attD[lane];
    int nCnt = min(BNODES, N - base);
    for (int nn = sub; nn < nCnt; nn += 4) {
        const float4* row4 = (const float4*)lds1[nn];
        float acc = 0.f;
        #pragma unroll
        for (int k4 = 0; k4 < 8; ++k4) {
            float4 rv = row4[k4];
            acc += rv.x*w2r[4*k4] + rv.y*w2r[4*k4+1] + rv.z*w2r[4*k4+2] + rv.w*w2r[4*k4+3];
        }
        int node = base + nn;
        h2h[(size_t)node*64 + lane] = __float2half(acc);
        float ps = acc * attSl;
        float pd = acc * attDl;
        #pragma unroll
        for (int mm = 1; mm < 8; mm <<= 1) {
            ps += __shfl_xor(ps, mm);
            pd += __shfl_xor(pd, mm);
        }
        int hh = lane >> 3, cc = lane & 7;
        if (cc == 0) aS[(size_t)node*8 + hh] = ps;
        if (cc == 1) aD[(size_t)node*8 + hh] = pd;
    }
}

// ---- layer 2 (R6 form): wave-per-node, no cross-lane ops in the main loop. ----
__global__ void k_agg(const unsigned* __restrict__ offsets, const int* __restrict__ ss,
                      const float* __restrict__ aS, const float* __restrict__ aD,
                      const __half* __restrict__ h2h, const float* __restrict__ b2,
                      const float* __restrict__ fcw, const float* __restrict__ fcb,
                      float* __restrict__ out, int N) {
    __shared__ int sl[4][MAXDEG];
    int lane = threadIdx.x & 63;
    int w = threadIdx.x >> 6;
    int d = blockIdx.x * 4 + w;
    if (d >= N) return;
    unsigned u = offsets[d];
    unsigned beg = u >> 10;
    int deg = (int)(u & 1023u);
    int lH   = lane & 31;      // channel pair: channels 2lH, 2lH+1 (same head always)
    int half = lane >> 5;      // 0 -> even edges, 1 -> odd edges
    int hh   = lH >> 2;        // head of my channel pair
    const __half2* __restrict__ hp = (const __half2*)h2h;
    float sum = 0.f, ax = 0.f, ay = 0.f;
    if (deg <= MAXDEG) {
        int degPad = (deg + 7) & ~7;
        for (int j = lane; j < degPad; j += 64) sl[w][j] = ss[beg + (unsigned)min(j, deg - 1)];
        float adv = aD[(unsigned)d * 8u + (unsigned)hh];
        for (int e = 0; e < degPad; e += 8) {
            int bi = e + half;
            int s0 = sl[w][bi],     s1 = sl[w][bi + 2];
            int s2 = sl[w][bi + 4], s3 = sl[w][bi + 6];
            float a0 = aS[(unsigned)s0 * 8u + (unsigned)hh];
            float a1 = aS[(unsigned)s1 * 8u + (unsigned)hh];
            float a2 = aS[(unsigned)s2 * 8u + (unsigned)hh];
            float a3 = aS[(unsigned)s3 * 8u + (unsigned)hh];
            float2 g0 = __half22float2(hp[(unsigned)s0 * 32u + (unsigned)lH]);
            float2 g1 = __half22float2(hp[(unsigned)s1 * 32u + (unsigned)lH]);
            float2 g2 = __half22float2(hp[(unsigned)s2 * 32u + (unsigned)lH]);
            float2 g3 = __half22float2(hp[(unsigned)s3 * 32u + (unsigned)lH]);
            float p0 = __expf(lrelu(a0 + adv));
            float p1 = __expf(lrelu(a1 + adv));
            float p2 = __expf(lrelu(a2 + adv));
            float p3 = __expf(lrelu(a3 + adv));
            if (e + 8 > deg) {             // wave-uniform branch, last group only
                if (bi     >= deg) p0 = 0.f;
                if (bi + 2 >= deg) p1 = 0.f;
                if (bi + 4 >= deg) p2 = 0.f;
                if (bi + 6 >= deg) p3 = 0.f;
            }
            ax += p0*g0.x + p1*g1.x + p2*g2.x + p3*g3.x;
            ay += p0*g0.y + p1*g1.y + p2*g2.y + p3*g3.y;
            sum += (p0 + p1) + (p2 + p3);
        }
    } else {
        // fallback (statistically never): halves take strided edges
        float adh = aD[(size_t)d*8 + hh];
        for (int e = half; e < deg; e += 2) {
            int s = ss[beg + e];
            float p = __expf(lrelu(aS[(size_t)s*8 + hh] + adh));
            float2 g = __half22float2(*(const __half2*)(h2h + (size_t)s*64 + 2*lH));
            ax += p*g.x; ay += p*g.y; sum += p;
        }
    }
    ax  += __shfl_xor(ax, 32);
    ay  += __shfl_xor(ay, 32);
    sum += __shfl_xor(sum, 32);
    float inv = 1.f / (sum + SEPS);
    float tt = elu1f(ax*inv + b2[2*lH]) * fcw[2*lH]
             + elu1f(ay*inv + b2[2*lH+1]) * fcw[2*lH+1];
    #pragma unroll
    for (int m = 16; m; m >>= 1) tt += __shfl_xor(tt, m);
    if (lane == 0) out[d] = tt + fcb[0];
}

extern "C" void kernel_launch(void* const* d_in, const int* in_sizes, int n_in,
                              void* d_out, int out_size, void* d_ws, size_t ws_size,
                              hipStream_t stream) {
    const float* x    = (const float*)d_in[0];
    const int*   ei   = (const int*)  d_in[1];
    const float* W1   = (const float*)d_in[2];
    const float* as1  = (const float*)d_in[3];
    const float* ad1  = (const float*)d_in[4];
    const float* b1   = (const float*)d_in[5];
    const float* W2   = (const float*)d_in[6];
    const float* attS2= (const float*)d_in[7];
    const float* attD2= (const float*)d_in[8];
    const float* b2   = (const float*)d_in[9];
    const float* fcw  = (const float*)d_in[10];
    const float* fcb  = (const float*)d_in[11];
    float* out = (float*)d_out;

    int N = in_sizes[0];          // x is [N,1]
    int E = in_sizes[1] / 2;      // edge_index is [2,E]
    int ET = E + N;               // with self-loops
    int NB = (N + BNODES - 1) / BNODES;   // 128-node coarse buckets (<= NBMAX)
    // padded bucket capacity: mean + 512 (~11 sigma for Binomial(ET,1/NB)), 4-aligned
    unsigned cap = (unsigned)((ET + NB - 1) / NB + 512);
    cap = (cap + 3u) & ~3u;
    size_t padded = (size_t)NB * cap;

    const int* srcI = ei;
    const int* dstI = ei + E;

    float* ws = (float*)d_ws;
    size_t off = 0;
    unsigned* bucketCursor = (unsigned*)(ws + off); off += (size_t)NBMAX * 16;
    unsigned* offsets      = (unsigned*)(ws + off); off += (size_t)N + 16;
    int*      pk           = (int*)(ws + off); off += padded;
    int*      sortedSrc    = (int*)(ws + off); off += padded;
    float*    aS2          = ws + off; off += (size_t)N * 8;
    float*    aD2          = ws + off; off += (size_t)N * 8;
    __half*   h2h          = (__half*)(ws + off); off += (size_t)N * 32;  // N*64 halves

    // cursor-as-offset: zero-init via DMA memset (replaces the k_prep kernel launch)
    hipMemsetAsync(bucketCursor, 0, (size_t)NBMAX * 16 * sizeof(unsigned), stream);

    int chunk = (ET + NCHUNK - 1) / NCHUNK;
    k_bscatter<<<NCHUNK, SCTPB, 0, stream>>>(srcI, dstI, E, N, NB, chunk, cap,
                                             bucketCursor, pk);
    k_sl1h2   <<<NB, TPB, 0, stream>>>(pk, bucketCursor, cap, x, as1, ad1, W1, b1,
                                       W2, attS2, attD2,
                                       N, offsets, sortedSrc, h2h, aS2, aD2);
    k_agg     <<<(N + 3) / 4, TPB, 0, stream>>>(offsets, sortedSrc, aS2, aD2, h2h,
                                                b2, fcw, fcb, out, N);
}

// Round 11
// 198.687 us; speedup vs baseline: 1.1889x; 1.0682x over previous
//
#include <hip/hip_runtime.h>
#include <hip/hip_fp16.h>
#include <cmath>

#define TPB 256
#define NSLOPE 0.2f
#define SEPS 1e-16f

#define BSH 7                 // nodes per bucket = 128
#define BNODES 128
#define NBMAX 1024            // supports N up to 131072 at BSH=7
#define NCHUNK 256            // blocks for bucket scatter (longer per-bucket runs)
#define SCTPB 1024            // bscatter threads
#define SCSTAGE 6720          // bscatter per-chunk LDS staging (chunk=6642 at N=100k)
#define STAGE 2816            // per-bucket LDS sorted-edge staging (cap=2688 at N=100k)
#define MAXDEG 96             // per-wave LDS edge staging cap (P[deg>96] ~ 0 for Poisson(17))

__device__ __forceinline__ float lrelu(float v) { return v > 0.f ? v : NSLOPE * v; }
__device__ __forceinline__ float elu1(float v)  { return v > 0.f ? v : expm1f(v); }
__device__ __forceinline__ float elu1f(float v) { return v > 0.f ? v : __expf(v) - 1.f; }

// ---- bucket scatter (cursor-as-offset, zero-init by memset): hist ->
//      hierarchical shfl scan -> claim -> LDS bucket-sort -> coalesced writes ----
__global__ void k_bscatter(const int* __restrict__ srcI, const int* __restrict__ dstI,
                           int E, int N, int NB, int chunk, unsigned cap,
                           unsigned* __restrict__ bucketCursor, int* __restrict__ pk) {
    __shared__ int cnt[NBMAX];
    __shared__ unsigned base[NBMAX];      // claimed per-bucket offsets
    __shared__ int offl[NBMAX];           // local exclusive prefix
    __shared__ int rval[SCSTAGE];
    __shared__ unsigned short rbkt[SCSTAGE];
    __shared__ int wtot[16], woff[16];    // wave-scan scratch
    int t = threadIdx.x;
    int lane = t & 63, wv = t >> 6;
    int ET = E + N;
    int beg = blockIdx.x * chunk;
    int end = min(beg + chunk, ET);
    int m = end - beg;
    for (int i = t; i < NBMAX; i += blockDim.x) cnt[i] = 0;
    __syncthreads();
    for (int e = beg + t; e < end; e += blockDim.x) {
        int d = (e < E) ? dstI[e] : (e - E);
        atomicAdd(&cnt[d >> BSH], 1);
    }
    __syncthreads();
    // hierarchical inclusive scan over NBMAX=1024 bins (SCTPB==NBMAX)
    int v = cnt[t];
    int inc = v;
    #pragma unroll
    for (int off = 1; off < 64; off <<= 1) {
        int u = __shfl_up(inc, off);
        if (lane >= off) inc += u;
    }
    if (lane == 63) wtot[wv] = inc;
    __syncthreads();
    if (t < 16) {
        int xv = wtot[t];
        int sc_ = xv;
        #pragma unroll
        for (int off = 1; off < 16; off <<= 1) {
            int u = __shfl_up(sc_, off);
            if (t >= off) sc_ += u;
        }
        woff[t] = sc_ - xv;   // exclusive wave offset
    }
    __syncthreads();
    offl[t] = inc + woff[wv] - v;   // exclusive prefix within chunk
    if (t < NB) {
        base[t] = v ? atomicAdd(&bucketCursor[(size_t)t * 16], (unsigned)v) : 0u;
        cnt[t] = 0;
    }
    __syncthreads();
    if (m <= SCSTAGE) {
        for (int e = beg + t; e < end; e += blockDim.x) {
            int s, d;
            if (e < E) { s = srcI[e]; d = dstI[e]; } else { s = d = e - E; }
            int b = d >> BSH;
            int r = atomicAdd(&cnt[b], 1);
            int slot = offl[b] + r;
            rval[slot] = (s << BSH) | (d & (BNODES - 1));
            rbkt[slot] = (unsigned short)b;
        }
        __syncthreads();
        for (int slot = t; slot < m; slot += blockDim.x) {
            int b = rbkt[slot];
            pk[(size_t)b * cap + base[b] + (unsigned)(slot - offl[b])] = rval[slot];
        }
    } else {
        for (int e = beg + t; e < end; e += blockDim.x) {
            int s, d;
            if (e < E) { s = srcI[e]; d = dstI[e]; } else { s = d = e - E; }
            int b = d >> BSH;
            int r = atomicAdd(&cnt[b], 1);
            pk[(size_t)b * cap + base[b] + (unsigned)r] = (s << BSH) | (d & (BNODES - 1));
        }
    }
}

// ---- merged sort + layer-1 + h2/att (R6 form): pk read ONCE (praw UNION lds1);
//      2-barrier shfl scan; per-block SD (k_prep eliminated). ----
__global__ void k_sl1h2(const int* __restrict__ pk, const unsigned* __restrict__ bucketCursor,
                        unsigned cap,
                        const float* __restrict__ x,
                        const float* __restrict__ as1, const float* __restrict__ ad1,
                        const float* __restrict__ W1, const float* __restrict__ b1,
                        const float* __restrict__ W2, const float* __restrict__ attS,
                        const float* __restrict__ attD, int N,
                        unsigned* __restrict__ offsets, int* __restrict__ sortedSrc,
                        __half* __restrict__ h2h, float* __restrict__ aS, float* __restrict__ aD) {
    __shared__ __align__(16) char upool[BNODES * 36 * 4];
    int* praw = (int*)upool;
    float (*lds1)[36] = (float (*)[36])upool;
    __shared__ int sorted[STAGE];
    __shared__ int cnt[BNODES];
    __shared__ int offl[BNODES];
    __shared__ float SDs[8];
    __shared__ int w0tot;
    int b = blockIdx.x, t = threadIdx.x;
    unsigned rbeg = (unsigned)b * cap;
    int m = (int)bucketCursor[(size_t)b * 16];
    bool inLds = (m <= STAGE);
    int base = b << BSH;
    if (t < BNODES) cnt[t] = 0;
    if (t < 8) {                           // per-block SD: S1[h] / D1[h]
        int h = t & 3;
        const float* att = (t >= 4) ? ad1 : as1;
        float acc = 0.f;
        #pragma unroll
        for (int c = 0; c < 8; ++c) acc += W1[h*8+c] * att[h*8+c];
        SDs[t] = acc;
    }
    __syncthreads();
    // pass 1: single global read of pk; stage into LDS + histogram
    if (inLds) {
        for (int i = t; i < m; i += TPB) {
            int p = pk[rbeg + i];
            praw[i] = p;
            atomicAdd(&cnt[p & (BNODES - 1)], 1);
        }
    } else {
        for (int i = t; i < m; i += TPB) atomicAdd(&cnt[pk[rbeg + i] & (BNODES - 1)], 1);
    }
    __syncthreads();
    // 128-bin exclusive prefix: per-wave shfl scan + single cross-wave fixup
    int v = (t < BNODES) ? cnt[t] : 0;
    int inc = v;
    #pragma unroll
    for (int off = 1; off < 64; off <<= 1) {
        int u = __shfl_up(inc, off);
        if ((t & 63) >= off) inc += u;
    }
    if (t == 63) w0tot = inc;
    __syncthreads();
    if (t >= 64 && t < BNODES) inc += w0tot;
    if (t < BNODES) {
        int ex = inc - v;
        int d = base + t;
        if (d < N) offsets[d] = ((rbeg + (unsigned)ex) << 10) | (unsigned)v;
        cnt[t] = 0;
        offl[t] = ex;
    }
    __syncthreads();
    // pass 2: reorder (LDS->LDS when staged), then coalesced global write
    if (inLds) {
        for (int i = t; i < m; i += TPB) {
            int p = praw[i];
            int dl = p & (BNODES - 1);
            int r = atomicAdd(&cnt[dl], 1);
            sorted[offl[dl] + r] = p >> BSH;
        }
        __syncthreads();
        for (int i = t; i < m; i += TPB) sortedSrc[rbeg + i] = sorted[i];
    } else {
        for (int i = t; i < m; i += TPB) {
            int p = pk[rbeg + i];
            int dl = p & (BNODES - 1);
            int r = atomicAdd(&cnt[dl], 1);
            sortedSrc[rbeg + (unsigned)(offl[dl] + r)] = p >> BSH;
        }
        __syncthreads();
    }
    __syncthreads();          // praw dead from here; lds1 live
    // layer-1 softmax: 2 threads/node; edge indices from LDS sorted[]
    int n = t >> 1, half = t & 1;
    int d2 = base + n;
    bool active = (d2 < N);
    float s0 = 0.f, s1 = 0.f, s2 = 0.f, s3 = 0.f;
    float g0 = 0.f, g1 = 0.f, g2 = 0.f, g3 = 0.f;
    if (active) {
        int deg = cnt[n];
        int lbeg = offl[n];
        float xd = x[d2];
        float S0 = SDs[0], S1 = SDs[1], S2 = SDs[2], S3 = SDs[3];
        float D0 = xd*SDs[4], D1 = xd*SDs[5], D2 = xd*SDs[6], D3 = xd*SDs[7];
        int dh = (deg + 1) >> 1;
        int i = lbeg + (half ? dh : 0);
        int rem = half ? (deg - dh) : dh;
        for (; rem >= 2; rem -= 2, i += 2) {
            int a0 = inLds ? sorted[i]   : sortedSrc[rbeg + i];
            int a1 = inLds ? sorted[i+1] : sortedSrc[rbeg + i + 1];
            float x0 = x[a0], x1 = x[a1];
            float p;
            p = __expf(lrelu(x0*S0 + D0)); s0 += p; g0 += p * x0;
            p = __expf(lrelu(x0*S1 + D1)); s1 += p; g1 += p * x0;
            p = __expf(lrelu(x0*S2 + D2)); s2 += p; g2 += p * x0;
            p = __expf(lrelu(x0*S3 + D3)); s3 += p; g3 += p * x0;
            p = __expf(lrelu(x1*S0 + D0)); s0 += p; g0 += p * x1;
            p = __expf(lrelu(x1*S1 + D1)); s1 += p; g1 += p * x1;
            p = __expf(lrelu(x1*S2 + D2)); s2 += p; g2 += p * x1;
            p = __expf(lrelu(x1*S3 + D3)); s3 += p; g3 += p * x1;
        }
        if (rem > 0) {
            int a0 = inLds ? sorted[i] : sortedSrc[rbeg + i];
            float xs = x[a0];
            float p;
            p = __expf(lrelu(xs*S0 + D0)); s0 += p; g0 += p * xs;
            p = __expf(lrelu(xs*S1 + D1)); s1 += p; g1 += p * xs;
            p = __expf(lrelu(xs*S2 + D2)); s2 += p; g2 += p * xs;
            p = __expf(lrelu(xs*S3 + D3)); s3 += p; g3 += p * xs;
        }
    }
    s0 += __shfl_xor(s0, 1); s1 += __shfl_xor(s1, 1);
    s2 += __shfl_xor(s2, 1); s3 += __shfl_xor(s3, 1);
    g0 += __shfl_xor(g0, 1); g1 += __shfl_xor(g1, 1);
    g2 += __shfl_xor(g2, 1); g3 += __shfl_xor(g3, 1);
    if (active) {
        float gg[4];
        gg[0] = g0 / (s0 + SEPS); gg[1] = g1 / (s1 + SEPS);
        gg[2] = g2 / (s2 + SEPS); gg[3] = g3 / (s3 + SEPS);
        int h0 = half * 2;                 // each half-thread writes 2 heads
        #pragma unroll
        for (int hh = 0; hh < 2; ++hh)
            #pragma unroll
            for (int cc = 0; cc < 8; ++cc)
                lds1[n][(h0+hh)*8+cc] = elu1(gg[h0+hh] * W1[(h0+hh)*8+cc] + b1[(h0+hh)*8+cc]);
    }
    __syncthreads();
    // h2 = lds1 @ W2 (+ att coeffs); W2 column in 32 VGPRs, row via b128 reads.
    int lane = t & 63;                    // channel j
    int sub = t >> 6;                     // wave id 0..3
    float w2r[32];
    #pragma unroll
    for (int k = 0; k < 32; ++k) w2r[k] = W2[k*64 + lane];
    float attSl = attS[lane], attDl = attD[lane];
    int nCnt = min(BNODES, N - base);
    for (int nn = sub; nn < nCnt; nn += 4) {
        const float4* row4 = (const float4*)lds1[nn];
        float acc = 0.f;
        #pragma unroll
        for (int k4 = 0; k4 < 8; ++k4) {
            float4 rv = row4[k4];
            acc += rv.x*w2r[4*k4] + rv.y*w2r[4*k4+1] + rv.z*w2r[4*k4+2] + rv.w*w2r[4*k4+3];
        }
        int node = base + nn;
        h2h[(size_t)node*64 + lane] = __float2half(acc);
        float ps = acc * attSl;
        float pd = acc * attDl;
        #pragma unroll
        for (int mm = 1; mm < 8; mm <<= 1) {
            ps += __shfl_xor(ps, mm);
            pd += __shfl_xor(pd, mm);
        }
        int hh = lane >> 3, cc = lane & 7;
        if (cc == 0) aS[(size_t)node*8 + hh] = ps;
        if (cc == 1) aD[(size_t)node*8 + hh] = pd;
    }
}

// ---- layer 2 (R6 form, node-range): wave-per-node, no cross-lane ops in the
//   main loop. Launched twice over [nodeBeg,nodeEnd) — traffic-neutral split
//   so each instance (~28us) vacates top-5 and bscatter/sl1h2 become visible. ----
__global__ void k_agg(const unsigned* __restrict__ offsets, const int* __restrict__ ss,
                      const float* __restrict__ aS, const float* __restrict__ aD,
                      const __half* __restrict__ h2h, const float* __restrict__ b2,
                      const float* __restrict__ fcw, const float* __restrict__ fcb,
                      float* __restrict__ out, int nodeBeg, int nodeEnd) {
    __shared__ int sl[4][MAXDEG];
    int lane = threadIdx.x & 63;
    int w = threadIdx.x >> 6;
    int d = nodeBeg + blockIdx.x * 4 + w;
    if (d >= nodeEnd) return;
    unsigned u = offsets[d];
    unsigned beg = u >> 10;
    int deg = (int)(u & 1023u);
    int lH   = lane & 31;      // channel pair: channels 2lH, 2lH+1 (same head always)
    int half = lane >> 5;      // 0 -> even edges, 1 -> odd edges
    int hh   = lH >> 2;        // head of my channel pair
    const __half2* __restrict__ hp = (const __half2*)h2h;
    float sum = 0.f, ax = 0.f, ay = 0.f;
    if (deg <= MAXDEG) {
        int degPad = (deg + 7) & ~7;
        for (int j = lane; j < degPad; j += 64) sl[w][j] = ss[beg + (unsigned)min(j, deg - 1)];
        float adv = aD[(unsigned)d * 8u + (unsigned)hh];
        for (int e = 0; e < degPad; e += 8) {
            int bi = e + half;
            int s0 = sl[w][bi],     s1 = sl[w][bi + 2];
            int s2 = sl[w][bi + 4], s3 = sl[w][bi + 6];
            float a0 = aS[(unsigned)s0 * 8u + (unsigned)hh];
            float a1 = aS[(unsigned)s1 * 8u + (unsigned)hh];
            float a2 = aS[(unsigned)s2 * 8u + (unsigned)hh];
            float a3 = aS[(unsigned)s3 * 8u + (unsigned)hh];
            float2 g0 = __half22float2(hp[(unsigned)s0 * 32u + (unsigned)lH]);
            float2 g1 = __half22float2(hp[(unsigned)s1 * 32u + (unsigned)lH]);
            float2 g2 = __half22float2(hp[(unsigned)s2 * 32u + (unsigned)lH]);
            float2 g3 = __half22float2(hp[(unsigned)s3 * 32u + (unsigned)lH]);
            float p0 = __expf(lrelu(a0 + adv));
            float p1 = __expf(lrelu(a1 + adv));
            float p2 = __expf(lrelu(a2 + adv));
            float p3 = __expf(lrelu(a3 + adv));
            if (e + 8 > deg) {             // wave-uniform branch, last group only
                if (bi     >= deg) p0 = 0.f;
                if (bi + 2 >= deg) p1 = 0.f;
                if (bi + 4 >= deg) p2 = 0.f;
                if (bi + 6 >= deg) p3 = 0.f;
            }
            ax += p0*g0.x + p1*g1.x + p2*g2.x + p3*g3.x;
            ay += p0*g0.y + p1*g1.y + p2*g2.y + p3*g3.y;
            sum += (p0 + p1) + (p2 + p3);
        }
    } else {
        // fallback (statistically never): halves take strided edges
        float adh = aD[(size_t)d*8 + hh];
        for (int e = half; e < deg; e += 2) {
            int s = ss[beg + e];
            float p = __expf(lrelu(aS[(size_t)s*8 + hh] + adh));
            float2 g = __half22float2(*(const __half2*)(h2h + (size_t)s*64 + 2*lH));
            ax += p*g.x; ay += p*g.y; sum += p;
        }
    }
    ax  += __shfl_xor(ax, 32);
    ay  += __shfl_xor(ay, 32);
    sum += __shfl_xor(sum, 32);
    float inv = 1.f / (sum + SEPS);
    float tt = elu1f(ax*inv + b2[2*lH]) * fcw[2*lH]
             + elu1f(ay*inv + b2[2*lH+1]) * fcw[2*lH+1];
    #pragma unroll
    for (int m = 16; m; m >>= 1) tt += __shfl_xor(tt, m);
    if (lane == 0) out[d] = tt + fcb[0];
}

extern "C" void kernel_launch(void* const* d_in, const int* in_sizes, int n_in,
                              void* d_out, int out_size, void* d_ws, size_t ws_size,
                              hipStream_t stream) {
    const float* x    = (const float*)d_in[0];
    const int*   ei   = (const int*)  d_in[1];
    const float* W1   = (const float*)d_in[2];
    const float* as1  = (const float*)d_in[3];
    const float* ad1  = (const float*)d_in[4];
    const float* b1   = (const float*)d_in[5];
    const float* W2   = (const float*)d_in[6];
    const float* attS2= (const float*)d_in[7];
    const float* attD2= (const float*)d_in[8];
    const float* b2   = (const float*)d_in[9];
    const float* fcw  = (const float*)d_in[10];
    const float* fcb  = (const float*)d_in[11];
    float* out = (float*)d_out;

    int N = in_sizes[0];          // x is [N,1]
    int E = in_sizes[1] / 2;      // edge_index is [2,E]
    int ET = E + N;               // with self-loops
    int NB = (N + BNODES - 1) / BNODES;   // 128-node coarse buckets (<= NBMAX)
    // padded bucket capacity: mean + 512 (~11 sigma for Binomial(ET,1/NB)), 4-aligned
    unsigned cap = (unsigned)((ET + NB - 1) / NB + 512);
    cap = (cap + 3u) & ~3u;
    size_t padded = (size_t)NB * cap;

    const int* srcI = ei;
    const int* dstI = ei + E;

    float* ws = (float*)d_ws;
    size_t off = 0;
    unsigned* bucketCursor = (unsigned*)(ws + off); off += (size_t)NBMAX * 16;
    unsigned* offsets      = (unsigned*)(ws + off); off += (size_t)N + 16;
    int*      pk           = (int*)(ws + off); off += padded;
    int*      sortedSrc    = (int*)(ws + off); off += padded;
    float*    aS2          = ws + off; off += (size_t)N * 8;
    float*    aD2          = ws + off; off += (size_t)N * 8;
    off = (off + 31) & ~(size_t)31;       // 128-B ALIGN h2h — R10's −24% was losing this
    __half*   h2h          = (__half*)(ws + off); off += (size_t)N * 32;  // N*64 halves

    // cursor-as-offset: zero-init via DMA memset (no k_prep kernel)
    hipMemsetAsync(bucketCursor, 0, (size_t)NBMAX * 16 * sizeof(unsigned), stream);

    int chunk = (ET + NCHUNK - 1) / NCHUNK;
    k_bscatter<<<NCHUNK, SCTPB, 0, stream>>>(srcI, dstI, E, N, NB, chunk, cap,
                                             bucketCursor, pk);
    k_sl1h2   <<<NB, TPB, 0, stream>>>(pk, bucketCursor, cap, x, as1, ad1, W1, b1,
                                       W2, attS2, attD2,
                                       N, offsets, sortedSrc, h2h, aS2, aD2);
    int Nh = ((N / 2) + 3) & ~3;          // block-aligned node split
    k_agg<<<(Nh + 3) / 4, TPB, 0, stream>>>(offsets, sortedSrc, aS2, aD2, h2h,
                                            b2, fcw, fcb, out, 0, Nh);
    k_agg<<<(N - Nh + 3) / 4, TPB, 0, stream>>>(offsets, sortedSrc, aS2, aD2, h2h,
                                                b2, fcw, fcb, out, Nh, N);
}

// Round 12
// 192.859 us; speedup vs baseline: 1.2248x; 1.0302x over previous
//
#include <hip/hip_runtime.h>
#include <hip/hip_fp16.h>
#include <cmath>

#define TPB 256
#define STPB 512              // k_sl1h2 threads (4/node in layer-1)
#define NSLOPE 0.2f
#define SEPS 1e-16f

#define BSH 7                 // nodes per bucket = 128
#define BNODES 128
#define NBMAX 1024            // supports N up to 131072 at BSH=7
#define NCHUNK 256            // blocks for bucket scatter (longer per-bucket runs)
#define SCTPB 1024            // bscatter threads
#define SCSTAGE 6720          // bscatter per-chunk LDS staging (chunk=6642 at N=100k)
#define STAGE 2816            // per-bucket LDS sorted-edge staging (cap=2688 at N=100k)
#define MAXDEG 96             // per-wave LDS edge staging cap (P[deg>96] ~ 0 for Poisson(17))

__device__ __forceinline__ float lrelu(float v) { return v > 0.f ? v : NSLOPE * v; }
__device__ __forceinline__ float elu1(float v)  { return v > 0.f ? v : expm1f(v); }
__device__ __forceinline__ float elu1f(float v) { return v > 0.f ? v : __expf(v) - 1.f; }

// ---- bucket scatter (cursor-as-offset, zero-init by memset): hist ->
//      hierarchical shfl scan -> claim -> LDS bucket-sort -> coalesced writes ----
__global__ void k_bscatter(const int* __restrict__ srcI, const int* __restrict__ dstI,
                           int E, int N, int NB, int chunk, unsigned cap,
                           unsigned* __restrict__ bucketCursor, int* __restrict__ pk) {
    __shared__ int cnt[NBMAX];
    __shared__ unsigned base[NBMAX];      // claimed per-bucket offsets
    __shared__ int offl[NBMAX];           // local exclusive prefix
    __shared__ int rval[SCSTAGE];
    __shared__ unsigned short rbkt[SCSTAGE];
    __shared__ int wtot[16], woff[16];    // wave-scan scratch
    int t = threadIdx.x;
    int lane = t & 63, wv = t >> 6;
    int ET = E + N;
    int beg = blockIdx.x * chunk;
    int end = min(beg + chunk, ET);
    int m = end - beg;
    for (int i = t; i < NBMAX; i += blockDim.x) cnt[i] = 0;
    __syncthreads();
    for (int e = beg + t; e < end; e += blockDim.x) {
        int d = (e < E) ? dstI[e] : (e - E);
        atomicAdd(&cnt[d >> BSH], 1);
    }
    __syncthreads();
    // hierarchical inclusive scan over NBMAX=1024 bins (SCTPB==NBMAX)
    int v = cnt[t];
    int inc = v;
    #pragma unroll
    for (int off = 1; off < 64; off <<= 1) {
        int u = __shfl_up(inc, off);
        if (lane >= off) inc += u;
    }
    if (lane == 63) wtot[wv] = inc;
    __syncthreads();
    if (t < 16) {
        int xv = wtot[t];
        int sc_ = xv;
        #pragma unroll
        for (int off = 1; off < 16; off <<= 1) {
            int u = __shfl_up(sc_, off);
            if (t >= off) sc_ += u;
        }
        woff[t] = sc_ - xv;   // exclusive wave offset
    }
    __syncthreads();
    offl[t] = inc + woff[wv] - v;   // exclusive prefix within chunk
    if (t < NB) {
        base[t] = v ? atomicAdd(&bucketCursor[(size_t)t * 16], (unsigned)v) : 0u;
        cnt[t] = 0;
    }
    __syncthreads();
    if (m <= SCSTAGE) {
        for (int e = beg + t; e < end; e += blockDim.x) {
            int s, d;
            if (e < E) { s = srcI[e]; d = dstI[e]; } else { s = d = e - E; }
            int b = d >> BSH;
            int r = atomicAdd(&cnt[b], 1);
            int slot = offl[b] + r;
            rval[slot] = (s << BSH) | (d & (BNODES - 1));
            rbkt[slot] = (unsigned short)b;
        }
        __syncthreads();
        for (int slot = t; slot < m; slot += blockDim.x) {
            int b = rbkt[slot];
            pk[(size_t)b * cap + base[b] + (unsigned)(slot - offl[b])] = rval[slot];
        }
    } else {
        for (int e = beg + t; e < end; e += blockDim.x) {
            int s, d;
            if (e < E) { s = srcI[e]; d = dstI[e]; } else { s = d = e - E; }
            int b = d >> BSH;
            int r = atomicAdd(&cnt[b], 1);
            pk[(size_t)b * cap + base[b] + (unsigned)r] = (s << BSH) | (d & (BNODES - 1));
        }
    }
}

// ---- merged sort + layer-1 + h2/att: 512 threads — 4 threads/node in layer-1
//      (halves the serial dependent-gather chain), hist/reorder passes 2x wider.
//      pk read ONCE (praw UNION lds1); 2-barrier shfl scan; per-block SD. ----
__global__ void k_sl1h2(const int* __restrict__ pk, const unsigned* __restrict__ bucketCursor,
                        unsigned cap,
                        const float* __restrict__ x,
                        const float* __restrict__ as1, const float* __restrict__ ad1,
                        const float* __restrict__ W1, const float* __restrict__ b1,
                        const float* __restrict__ W2, const float* __restrict__ attS,
                        const float* __restrict__ attD, int N,
                        unsigned* __restrict__ offsets, int* __restrict__ sortedSrc,
                        __half* __restrict__ h2h, float* __restrict__ aS, float* __restrict__ aD) {
    __shared__ __align__(16) char upool[BNODES * 36 * 4];
    int* praw = (int*)upool;
    float (*lds1)[36] = (float (*)[36])upool;
    __shared__ int sorted[STAGE];
    __shared__ int cnt[BNODES];
    __shared__ int offl[BNODES];
    __shared__ float SDs[8];
    __shared__ int w0tot;
    int b = blockIdx.x, t = threadIdx.x;
    unsigned rbeg = (unsigned)b * cap;
    int m = (int)bucketCursor[(size_t)b * 16];
    bool inLds = (m <= STAGE);
    int base = b << BSH;
    if (t < BNODES) cnt[t] = 0;
    if (t < 8) {                           // per-block SD: S1[h] / D1[h]
        int h = t & 3;
        const float* att = (t >= 4) ? ad1 : as1;
        float acc = 0.f;
        #pragma unroll
        for (int c = 0; c < 8; ++c) acc += W1[h*8+c] * att[h*8+c];
        SDs[t] = acc;
    }
    __syncthreads();
    // pass 1: single global read of pk; stage into LDS + histogram
    if (inLds) {
        for (int i = t; i < m; i += STPB) {
            int p = pk[rbeg + i];
            praw[i] = p;
            atomicAdd(&cnt[p & (BNODES - 1)], 1);
        }
    } else {
        for (int i = t; i < m; i += STPB) atomicAdd(&cnt[pk[rbeg + i] & (BNODES - 1)], 1);
    }
    __syncthreads();
    // 128-bin exclusive prefix: per-wave shfl scan + single cross-wave fixup
    int v = (t < BNODES) ? cnt[t] : 0;
    int inc = v;
    #pragma unroll
    for (int off = 1; off < 64; off <<= 1) {
        int u = __shfl_up(inc, off);
        if ((t & 63) >= off) inc += u;
    }
    if (t == 63) w0tot = inc;
    __syncthreads();
    if (t >= 64 && t < BNODES) inc += w0tot;
    if (t < BNODES) {
        int ex = inc - v;
        int d = base + t;
        if (d < N) offsets[d] = ((rbeg + (unsigned)ex) << 10) | (unsigned)v;
        cnt[t] = 0;
        offl[t] = ex;
    }
    __syncthreads();
    // pass 2: reorder (LDS->LDS when staged), then coalesced global write
    if (inLds) {
        for (int i = t; i < m; i += STPB) {
            int p = praw[i];
            int dl = p & (BNODES - 1);
            int r = atomicAdd(&cnt[dl], 1);
            sorted[offl[dl] + r] = p >> BSH;
        }
        __syncthreads();
        for (int i = t; i < m; i += STPB) sortedSrc[rbeg + i] = sorted[i];
    } else {
        for (int i = t; i < m; i += STPB) {
            int p = pk[rbeg + i];
            int dl = p & (BNODES - 1);
            int r = atomicAdd(&cnt[dl], 1);
            sortedSrc[rbeg + (unsigned)(offl[dl] + r)] = p >> BSH;
        }
        __syncthreads();
    }
    __syncthreads();          // praw dead from here; lds1 live
    // layer-1 softmax: 4 threads/node (quarter-split of deg)
    int n = t >> 2, q = t & 3;
    int d2 = base + n;
    bool active = (d2 < N);
    float s0 = 0.f, s1 = 0.f, s2 = 0.f, s3 = 0.f;
    float g0 = 0.f, g1 = 0.f, g2 = 0.f, g3 = 0.f;
    if (active) {
        int deg = cnt[n];
        int lbeg = offl[n];
        float xd = x[d2];
        float S0 = SDs[0], S1 = SDs[1], S2 = SDs[2], S3 = SDs[3];
        float D0 = xd*SDs[4], D1 = xd*SDs[5], D2 = xd*SDs[6], D3 = xd*SDs[7];
        int dq = (deg + 3) >> 2;
        int i = lbeg + q * dq;
        int rem = min(dq, deg - q * dq);   // may be <= 0 for high quarters
        for (; rem >= 2; rem -= 2, i += 2) {
            int a0 = inLds ? sorted[i]   : sortedSrc[rbeg + i];
            int a1 = inLds ? sorted[i+1] : sortedSrc[rbeg + i + 1];
            float x0 = x[a0], x1 = x[a1];
            float p;
            p = __expf(lrelu(x0*S0 + D0)); s0 += p; g0 += p * x0;
            p = __expf(lrelu(x0*S1 + D1)); s1 += p; g1 += p * x0;
            p = __expf(lrelu(x0*S2 + D2)); s2 += p; g2 += p * x0;
            p = __expf(lrelu(x0*S3 + D3)); s3 += p; g3 += p * x0;
            p = __expf(lrelu(x1*S0 + D0)); s0 += p; g0 += p * x1;
            p = __expf(lrelu(x1*S1 + D1)); s1 += p; g1 += p * x1;
            p = __expf(lrelu(x1*S2 + D2)); s2 += p; g2 += p * x1;
            p = __expf(lrelu(x1*S3 + D3)); s3 += p; g3 += p * x1;
        }
        if (rem > 0) {
            int a0 = inLds ? sorted[i] : sortedSrc[rbeg + i];
            float xs = x[a0];
            float p;
            p = __expf(lrelu(xs*S0 + D0)); s0 += p; g0 += p * xs;
            p = __expf(lrelu(xs*S1 + D1)); s1 += p; g1 += p * xs;
            p = __expf(lrelu(xs*S2 + D2)); s2 += p; g2 += p * xs;
            p = __expf(lrelu(xs*S3 + D3)); s3 += p; g3 += p * xs;
        }
    }
    // 4-lane butterfly: all 4 lanes of a node get full head sums
    s0 += __shfl_xor(s0, 1); s1 += __shfl_xor(s1, 1);
    s2 += __shfl_xor(s2, 1); s3 += __shfl_xor(s3, 1);
    g0 += __shfl_xor(g0, 1); g1 += __shfl_xor(g1, 1);
    g2 += __shfl_xor(g2, 1); g3 += __shfl_xor(g3, 1);
    s0 += __shfl_xor(s0, 2); s1 += __shfl_xor(s1, 2);
    s2 += __shfl_xor(s2, 2); s3 += __shfl_xor(s3, 2);
    g0 += __shfl_xor(g0, 2); g1 += __shfl_xor(g1, 2);
    g2 += __shfl_xor(g2, 2); g3 += __shfl_xor(g3, 2);
    if (active) {
        float gq = (q == 0) ? g0 / (s0 + SEPS) :
                   (q == 1) ? g1 / (s1 + SEPS) :
                   (q == 2) ? g2 / (s2 + SEPS) :
                              g3 / (s3 + SEPS);
        #pragma unroll
        for (int cc = 0; cc < 8; ++cc)      // lane q writes head q
            lds1[n][q*8+cc] = elu1(gq * W1[q*8+cc] + b1[q*8+cc]);
    }
    __syncthreads();
    // h2 = lds1 @ W2 (+ att coeffs); W2 column in 32 VGPRs, row via b128 reads.
    int lane = t & 63;                    // channel j
    int sub = t >> 6;                     // wave id 0..7
    float w2r[32];
    #pragma unroll
    for (int k = 0; k < 32; ++k) w2r[k] = W2[k*64 + lane];
    float attSl = attS[lane], attDl = attD[lane];
    int nCnt = min(BNODES, N - base);
    for (int nn = sub; nn < nCnt; nn += 8) {
        const float4* row4 = (const float4*)lds1[nn];
        float acc = 0.f;
        #pragma unroll
        for (int k4 = 0; k4 < 8; ++k4) {
            float4 rv = row4[k4];
            acc += rv.x*w2r[4*k4] + rv.y*w2r[4*k4+1] + rv.z*w2r[4*k4+2] + rv.w*w2r[4*k4+3];
        }
        int node = base + nn;
        h2h[(size_t)node*64 + lane] = __float2half(acc);
        float ps = acc * attSl;
        float pd = acc * attDl;
        #pragma unroll
        for (int mm = 1; mm < 8; mm <<= 1) {
            ps += __shfl_xor(ps, mm);
            pd += __shfl_xor(pd, mm);
        }
        int hh = lane >> 3, cc = lane & 7;
        if (cc == 0) aS[(size_t)node*8 + hh] = ps;
        if (cc == 1) aD[(size_t)node*8 + hh] = pd;
    }
}

// ---- layer 2 (R6 single-launch form): wave-per-node, no cross-lane ops. ----
__global__ void k_agg(const unsigned* __restrict__ offsets, const int* __restrict__ ss,
                      const float* __restrict__ aS, const float* __restrict__ aD,
                      const __half* __restrict__ h2h, const float* __restrict__ b2,
                      const float* __restrict__ fcw, const float* __restrict__ fcb,
                      float* __restrict__ out, int N) {
    __shared__ int sl[4][MAXDEG];
    int lane = threadIdx.x & 63;
    int w = threadIdx.x >> 6;
    int d = blockIdx.x * 4 + w;
    if (d >= N) return;
    unsigned u = offsets[d];
    unsigned beg = u >> 10;
    int deg = (int)(u & 1023u);
    int lH   = lane & 31;      // channel pair: channels 2lH, 2lH+1 (same head always)
    int half = lane >> 5;      // 0 -> even edges, 1 -> odd edges
    int hh   = lH >> 2;        // head of my channel pair
    const __half2* __restrict__ hp = (const __half2*)h2h;
    float sum = 0.f, ax = 0.f, ay = 0.f;
    if (deg <= MAXDEG) {
        int degPad = (deg + 7) & ~7;
        for (int j = lane; j < degPad; j += 64) sl[w][j] = ss[beg + (unsigned)min(j, deg - 1)];
        float adv = aD[(unsigned)d * 8u + (unsigned)hh];
        for (int e = 0; e < degPad; e += 8) {
            int bi = e + half;
            int s0 = sl[w][bi],     s1 = sl[w][bi + 2];
            int s2 = sl[w][bi + 4], s3 = sl[w][bi + 6];
            float a0 = aS[(unsigned)s0 * 8u + (unsigned)hh];
            float a1 = aS[(unsigned)s1 * 8u + (unsigned)hh];
            float a2 = aS[(unsigned)s2 * 8u + (unsigned)hh];
            float a3 = aS[(unsigned)s3 * 8u + (unsigned)hh];
            float2 g0 = __half22float2(hp[(unsigned)s0 * 32u + (unsigned)lH]);
            float2 g1 = __half22float2(hp[(unsigned)s1 * 32u + (unsigned)lH]);
            float2 g2 = __half22float2(hp[(unsigned)s2 * 32u + (unsigned)lH]);
            float2 g3 = __half22float2(hp[(unsigned)s3 * 32u + (unsigned)lH]);
            float p0 = __expf(lrelu(a0 + adv));
            float p1 = __expf(lrelu(a1 + adv));
            float p2 = __expf(lrelu(a2 + adv));
            float p3 = __expf(lrelu(a3 + adv));
            if (e + 8 > deg) {             // wave-uniform branch, last group only
                if (bi     >= deg) p0 = 0.f;
                if (bi + 2 >= deg) p1 = 0.f;
                if (bi + 4 >= deg) p2 = 0.f;
                if (bi + 6 >= deg) p3 = 0.f;
            }
            ax += p0*g0.x + p1*g1.x + p2*g2.x + p3*g3.x;
            ay += p0*g0.y + p1*g1.y + p2*g2.y + p3*g3.y;
            sum += (p0 + p1) + (p2 + p3);
        }
    } else {
        // fallback (statistically never): halves take strided edges
        float adh = aD[(size_t)d*8 + hh];
        for (int e = half; e < deg; e += 2) {
            int s = ss[beg + e];
            float p = __expf(lrelu(aS[(size_t)s*8 + hh] + adh));
            float2 g = __half22float2(*(const __half2*)(h2h + (size_t)s*64 + 2*lH));
            ax += p*g.x; ay += p*g.y; sum += p;
        }
    }
    ax  += __shfl_xor(ax, 32);
    ay  += __shfl_xor(ay, 32);
    sum += __shfl_xor(sum, 32);
    float inv = 1.f / (sum + SEPS);
    float tt = elu1f(ax*inv + b2[2*lH]) * fcw[2*lH]
             + elu1f(ay*inv + b2[2*lH+1]) * fcw[2*lH+1];
    #pragma unroll
    for (int m = 16; m; m >>= 1) tt += __shfl_xor(tt, m);
    if (lane == 0) out[d] = tt + fcb[0];
}

extern "C" void kernel_launch(void* const* d_in, const int* in_sizes, int n_in,
                              void* d_out, int out_size, void* d_ws, size_t ws_size,
                              hipStream_t stream) {
    const float* x    = (const float*)d_in[0];
    const int*   ei   = (const int*)  d_in[1];
    const float* W1   = (const float*)d_in[2];
    const float* as1  = (const float*)d_in[3];
    const float* ad1  = (const float*)d_in[4];
    const float* b1   = (const float*)d_in[5];
    const float* W2   = (const float*)d_in[6];
    const float* attS2= (const float*)d_in[7];
    const float* attD2= (const float*)d_in[8];
    const float* b2   = (const float*)d_in[9];
    const float* fcw  = (const float*)d_in[10];
    const float* fcb  = (const float*)d_in[11];
    float* out = (float*)d_out;

    int N = in_sizes[0];          // x is [N,1]
    int E = in_sizes[1] / 2;      // edge_index is [2,E]
    int ET = E + N;               // with self-loops
    int NB = (N + BNODES - 1) / BNODES;   // 128-node coarse buckets (<= NBMAX)
    // padded bucket capacity: mean + 512 (~11 sigma for Binomial(ET,1/NB)), 4-aligned
    unsigned cap = (unsigned)((ET + NB - 1) / NB + 512);
    cap = (cap + 3u) & ~3u;
    size_t padded = (size_t)NB * cap;

    const int* srcI = ei;
    const int* dstI = ei + E;

    float* ws = (float*)d_ws;
    size_t off = 0;
    unsigned* bucketCursor = (unsigned*)(ws + off); off += (size_t)NBMAX * 16;
    unsigned* offsets      = (unsigned*)(ws + off); off += (size_t)N + 16;
    int*      pk           = (int*)(ws + off); off += padded;
    int*      sortedSrc    = (int*)(ws + off); off += padded;
    float*    aS2          = ws + off; off += (size_t)N * 8;
    float*    aD2          = ws + off; off += (size_t)N * 8;
    off = (off + 31) & ~(size_t)31;       // 128-B ALIGN h2h (R10: losing this cost 24%)
    __half*   h2h          = (__half*)(ws + off); off += (size_t)N * 32;  // N*64 halves

    // cursor-as-offset: zero-init via DMA memset (no k_prep kernel)
    hipMemsetAsync(bucketCursor, 0, (size_t)NBMAX * 16 * sizeof(unsigned), stream);

    int chunk = (ET + NCHUNK - 1) / NCHUNK;
    k_bscatter<<<NCHUNK, SCTPB, 0, stream>>>(srcI, dstI, E, N, NB, chunk, cap,
                                             bucketCursor, pk);
    k_sl1h2   <<<NB, STPB, 0, stream>>>(pk, bucketCursor, cap, x, as1, ad1, W1, b1,
                                        W2, attS2, attD2,
                                        N, offsets, sortedSrc, h2h, aS2, aD2);
    k_agg     <<<(N + 3) / 4, TPB, 0, stream>>>(offsets, sortedSrc, aS2, aD2, h2h,
                                                b2, fcw, fcb, out, N);
}